// Round 5
// baseline (322.778 us; speedup 1.0000x reference)
//
#include <hip/hip_runtime.h>
#include <stdint.h>

namespace {
constexpr int B_ = 32;
constexpr int T_ = 2048;
constexpr int K_ = 512;
constexpr int MM = 1024;   // MAX_MASKED
constexpr int MU = 1024;   // MAX_UNMASKED
constexpr float EPS = 1e-5f;
constexpr int ROWS0 = B_ * MU;   // unmasked_embeddings rows
constexpr int ROWS1 = B_ * MM;   // mask_embedding rows
constexpr int WAVES_PER_BLOCK = 4;

// Native clang vector type: __builtin_nontemporal_* requires scalar or
// native-vector pointee (HIP_vector_type float4 is rejected — R4 compile err).
typedef float v4f __attribute__((ext_vector_type(4)));

__device__ inline v4f nt_load4(const float* p) {
    return __builtin_nontemporal_load((const v4f*)p);
}
__device__ inline void nt_store4(float* p, v4f v) {
    __builtin_nontemporal_store(v, (v4f*)p);
}
__device__ inline v4f ld4(const float* p) { return *(const v4f*)p; }
}  // namespace

// FP32 in / FP32 out (confirmed R3: pass at absmax 7.8e-3 = ref bf16 floor).
// One wave (64 lanes) per output row of K=512: 8 fp32 = 32 B/lane in & out.
// Per-wave branches are uniform. Output written once, never re-read -> nt
// stores. Token rows read once -> nt loads. pe (4 MB, re-read) stays cached.
__global__ __launch_bounds__(256) void mae_mask_kernel(
    const float* __restrict__ tok,      // (B,T,K)
    const float* __restrict__ pe,       // (T,K)
    const float* __restrict__ mw,       // (K,1)
    const float* __restrict__ gamma,    // (K,)
    const float* __restrict__ beta,     // (K,)
    const int* __restrict__ mask_idx,   // (B,MM)
    const int* __restrict__ unmask_idx, // (B,MU)
    const int* __restrict__ n_m,        // (B,)
    const int* __restrict__ n_u,        // (B,)
    float* __restrict__ out)            // 3*B*1024*K fp32
{
    const int lane = threadIdx.x & 63;
    const int wave = threadIdx.x >> 6;
    const int row  = blockIdx.x * WAVES_PER_BLOCK + wave;
    const int c    = lane << 3;  // starting element, 8 fp32 per lane

    float* orow = out + (size_t)row * K_ + c;

    if (row < ROWS0) {
        // ---- unmasked_embeddings: gather token rows ----
        const int b = row >> 10, j = row & (MU - 1);
        v4f v0 = (v4f)(0.f), v1 = (v4f)(0.f);
        if (j < n_u[b]) {
            const int idx = unmask_idx[(b << 10) + j];
            const float* src = tok + ((size_t)b * T_ + (size_t)idx) * K_ + c;
            v0 = nt_load4(src); v1 = nt_load4(src + 4);
        }
        nt_store4(orow, v0); nt_store4(orow + 4, v1);
    } else if (row < ROWS0 + ROWS1) {
        // ---- mask_embedding: LN(mask_weight + pe[mask_idx]) ----
        const int r = row - ROWS0;
        const int b = r >> 10, i = r & (MM - 1);
        v4f o0 = (v4f)(0.f), o1 = (v4f)(0.f);
        if (i < n_m[b]) {
            const int idx = mask_idx[(b << 10) + i];
            const float* pv = pe + (size_t)idx * K_ + c;
            const v4f p0 = ld4(pv), p1 = ld4(pv + 4);
            const v4f m0 = ld4(mw + c), m1 = ld4(mw + c + 4);
            float x[8] = { p0.x + m0.x, p0.y + m0.y, p0.z + m0.z, p0.w + m0.w,
                           p1.x + m1.x, p1.y + m1.y, p1.z + m1.z, p1.w + m1.w };
            float s = 0.f, ss = 0.f;
            #pragma unroll
            for (int e = 0; e < 8; ++e) { s += x[e]; ss += x[e] * x[e]; }
            // 64-lane butterfly reduction (wave = 64 on gfx950)
            #pragma unroll
            for (int off = 1; off < 64; off <<= 1) {
                s  += __shfl_xor(s,  off, 64);
                ss += __shfl_xor(ss, off, 64);
            }
            const float mean = s * (1.0f / K_);
            float var = ss * (1.0f / K_) - mean * mean;
            var = var < 0.f ? 0.f : var;
            const float inv = rsqrtf(var + EPS);
            const v4f g0 = ld4(gamma + c), g1 = ld4(gamma + c + 4);
            const v4f b0 = ld4(beta + c),  b1 = ld4(beta + c + 4);
            const float g[8]  = { g0.x, g0.y, g0.z, g0.w, g1.x, g1.y, g1.z, g1.w };
            const float be[8] = { b0.x, b0.y, b0.z, b0.w, b1.x, b1.y, b1.z, b1.w };
            float y[8];
            #pragma unroll
            for (int e = 0; e < 8; ++e) y[e] = (x[e] - mean) * inv * g[e] + be[e];
            o0 = (v4f){ y[0], y[1], y[2], y[3] };
            o1 = (v4f){ y[4], y[5], y[6], y[7] };
        }
        nt_store4(orow, o0); nt_store4(orow + 4, o1);
    } else {
        // ---- unmasked_positions: gather pe rows ----
        const int r = row - (ROWS0 + ROWS1);
        const int b = r >> 10, j = r & (MU - 1);
        v4f v0 = (v4f)(0.f), v1 = (v4f)(0.f);
        if (j < n_u[b]) {
            const int idx = unmask_idx[(b << 10) + j];
            const float* src = pe + (size_t)idx * K_ + c;
            v0 = ld4(src); v1 = ld4(src + 4);
        }
        nt_store4(orow, v0); nt_store4(orow + 4, v1);
    }
}

extern "C" void kernel_launch(void* const* d_in, const int* in_sizes, int n_in,
                              void* d_out, int out_size, void* d_ws, size_t ws_size,
                              hipStream_t stream) {
    const float* tok   = (const float*)d_in[0];
    const float* pe    = (const float*)d_in[1];
    const float* mw    = (const float*)d_in[2];
    const float* gamma = (const float*)d_in[3];
    const float* beta  = (const float*)d_in[4];
    const int* mask_idx   = (const int*)d_in[5];
    const int* unmask_idx = (const int*)d_in[6];
    const int* n_m        = (const int*)d_in[7];
    const int* n_u        = (const int*)d_in[8];
    float* out = (float*)d_out;

    const int total_rows = 3 * B_ * 1024;               // 98304
    const int blocks = total_rows / WAVES_PER_BLOCK;    // 24576
    hipLaunchKernelGGL(mae_mask_kernel, dim3(blocks), dim3(256), 0, stream,
                       tok, pe, mw, gamma, beta, mask_idx, unmask_idx,
                       n_m, n_u, out);
}

// Round 6
// 289.701 us; speedup vs baseline: 1.1142x; 1.1142x over previous
//
#include <hip/hip_runtime.h>
#include <stdint.h>

namespace {
constexpr int B_ = 32;
constexpr int T_ = 2048;
constexpr int K_ = 512;
constexpr int MM = 1024;   // MAX_MASKED
constexpr int MU = 1024;   // MAX_UNMASKED
constexpr float EPS = 1e-5f;
constexpr int ROWS0 = B_ * MU;   // unmasked_embeddings rows
constexpr int ROWS1 = B_ * MM;   // mask_embedding rows
constexpr int WAVES_PER_BLOCK = 4;
}  // namespace

// FP32 in / FP32 out (R3: pass, absmax 7.8e-3 = ref bf16 floor).
// One wave (64 lanes) per output row of K=512: 8 fp32 = 32 B/lane in & out.
// Per-wave branches are uniform (each wave handles exactly one region).
// NOTE R5: __builtin_nontemporal_* on these streams REGRESSED the kernel
// ~44 -> ~76 us (nt store defeats L2 write-combining; nt load defeats
// intra-row line reuse). Plain cached float4 accesses are the optimum here.
__global__ __launch_bounds__(256) void mae_mask_kernel(
    const float* __restrict__ tok,      // (B,T,K)
    const float* __restrict__ pe,       // (T,K)
    const float* __restrict__ mw,       // (K,1)
    const float* __restrict__ gamma,    // (K,)
    const float* __restrict__ beta,     // (K,)
    const int* __restrict__ mask_idx,   // (B,MM)
    const int* __restrict__ unmask_idx, // (B,MU)
    const int* __restrict__ n_m,        // (B,)
    const int* __restrict__ n_u,        // (B,)
    float* __restrict__ out)            // 3*B*1024*K fp32
{
    const int lane = threadIdx.x & 63;
    const int wave = threadIdx.x >> 6;
    const int row  = blockIdx.x * WAVES_PER_BLOCK + wave;
    const int c    = lane << 3;  // starting element, 8 fp32 per lane

    float4* orow = (float4*)(out + (size_t)row * K_ + c);

    if (row < ROWS0) {
        // ---- unmasked_embeddings: gather token rows ----
        const int b = row >> 10, j = row & (MU - 1);
        float4 v0 = make_float4(0.f, 0.f, 0.f, 0.f), v1 = v0;
        if (j < n_u[b]) {
            const int idx = unmask_idx[(b << 10) + j];
            const float4* src = (const float4*)(tok + ((size_t)b * T_ + (size_t)idx) * K_ + c);
            v0 = src[0]; v1 = src[1];
        }
        orow[0] = v0; orow[1] = v1;
    } else if (row < ROWS0 + ROWS1) {
        // ---- mask_embedding: LN(mask_weight + pe[mask_idx]) ----
        const int r = row - ROWS0;
        const int b = r >> 10, i = r & (MM - 1);
        float4 o0 = make_float4(0.f, 0.f, 0.f, 0.f), o1 = o0;
        if (i < n_m[b]) {
            const int idx = mask_idx[(b << 10) + i];
            const float4* pv = (const float4*)(pe + (size_t)idx * K_ + c);
            const float4* mv = (const float4*)(mw + c);
            const float4 p0 = pv[0], p1 = pv[1];
            const float4 m0 = mv[0], m1 = mv[1];
            float x[8] = { p0.x + m0.x, p0.y + m0.y, p0.z + m0.z, p0.w + m0.w,
                           p1.x + m1.x, p1.y + m1.y, p1.z + m1.z, p1.w + m1.w };
            float s = 0.f, ss = 0.f;
            #pragma unroll
            for (int e = 0; e < 8; ++e) { s += x[e]; ss += x[e] * x[e]; }
            // 64-lane butterfly reduction (wave = 64 on gfx950)
            #pragma unroll
            for (int off = 1; off < 64; off <<= 1) {
                s  += __shfl_xor(s,  off, 64);
                ss += __shfl_xor(ss, off, 64);
            }
            const float mean = s * (1.0f / K_);
            float var = ss * (1.0f / K_) - mean * mean;
            var = var < 0.f ? 0.f : var;
            const float inv = rsqrtf(var + EPS);
            const float4* gv = (const float4*)(gamma + c);
            const float4* bv = (const float4*)(beta + c);
            const float4 g0 = gv[0], g1 = gv[1];
            const float4 b0 = bv[0], b1 = bv[1];
            const float g[8]  = { g0.x, g0.y, g0.z, g0.w, g1.x, g1.y, g1.z, g1.w };
            const float be[8] = { b0.x, b0.y, b0.z, b0.w, b1.x, b1.y, b1.z, b1.w };
            float y[8];
            #pragma unroll
            for (int e = 0; e < 8; ++e) y[e] = (x[e] - mean) * inv * g[e] + be[e];
            o0 = make_float4(y[0], y[1], y[2], y[3]);
            o1 = make_float4(y[4], y[5], y[6], y[7]);
        }
        orow[0] = o0; orow[1] = o1;
    } else {
        // ---- unmasked_positions: gather pe rows ----
        const int r = row - (ROWS0 + ROWS1);
        const int b = r >> 10, j = r & (MU - 1);
        float4 v0 = make_float4(0.f, 0.f, 0.f, 0.f), v1 = v0;
        if (j < n_u[b]) {
            const int idx = unmask_idx[(b << 10) + j];
            const float4* src = (const float4*)(pe + (size_t)idx * K_ + c);
            v0 = src[0]; v1 = src[1];
        }
        orow[0] = v0; orow[1] = v1;
    }
}

extern "C" void kernel_launch(void* const* d_in, const int* in_sizes, int n_in,
                              void* d_out, int out_size, void* d_ws, size_t ws_size,
                              hipStream_t stream) {
    const float* tok   = (const float*)d_in[0];
    const float* pe    = (const float*)d_in[1];
    const float* mw    = (const float*)d_in[2];
    const float* gamma = (const float*)d_in[3];
    const float* beta  = (const float*)d_in[4];
    const int* mask_idx   = (const int*)d_in[5];
    const int* unmask_idx = (const int*)d_in[6];
    const int* n_m        = (const int*)d_in[7];
    const int* n_u        = (const int*)d_in[8];
    float* out = (float*)d_out;

    const int total_rows = 3 * B_ * 1024;               // 98304
    const int blocks = total_rows / WAVES_PER_BLOCK;    // 24576
    hipLaunchKernelGGL(mae_mask_kernel, dim3(blocks), dim3(256), 0, stream,
                       tok, pe, mw, gamma, beta, mask_idx, unmask_idx,
                       n_m, n_u, out);
}